// Round 10
// baseline (1404.578 us; speedup 1.0000x reference)
//
#include <hip/hip_runtime.h>
#include <cstdint>
#include <cstddef>

typedef __bf16 bf16;
typedef __bf16 bf16x4 __attribute__((ext_vector_type(4)));
typedef __bf16 bf16x8 __attribute__((ext_vector_type(8)));
typedef float  f32x4  __attribute__((ext_vector_type(4)));

#define NE   12     // experts
#define DDIM 1024   // D
#define HDIM 2048   // H
#define MDIM 1024   // H/2
#define ODIM 1024   // O
#define GG1  256
#define GG2  128
#define BB   4096
// Sum of per-expert counts == 4*BB == 16384 exactly. Padded to 128/expert:
// total rows <= 16384 + 12*127 = 17908 < 18432.
#define ROWS_MAX 18432
#define NXCD 8

#define GPTR(p) ((const __attribute__((address_space(1))) void*)(p))
#define LPTR(p) ((__attribute__((address_space(3))) void*)(p))

// ---------------------------------------------------------------- converts
__global__ void cvt_f32_bf16(const float* __restrict__ in, bf16* __restrict__ out) {
    size_t i = ((size_t)blockIdx.x * 256 + threadIdx.x) * 4;
    float4 v = *(const float4*)(in + i);
    bf16x4 o = { (bf16)v.x, (bf16)v.y, (bf16)v.z, (bf16)v.w };
    *(bf16x4*)(out + i) = o;
}

// in: [E][K,N] f32 -> out: [E][N,K] bf16. 64x64 tiles, 256 threads. (r8-proven)
__global__ __launch_bounds__(256)
void transpose_cvt(const float* __restrict__ in, bf16* __restrict__ out,
                   int K, int N) {
    __shared__ float tile[64][65];
    const size_t eo = (size_t)blockIdx.z * K * N;
    in  += eo;
    out += eo;
    const int n0 = blockIdx.x * 64, k0 = blockIdx.y * 64;
    const int tid = threadIdx.x;

    const int rkk = tid >> 4, rnc = (tid & 15) * 4;
    #pragma unroll
    for (int p = 0; p < 4; ++p) {
        const int kk = p * 16 + rkk;
        const float4 v = *(const float4*)(in + (size_t)(k0 + kk) * N + n0 + rnc);
        tile[kk][rnc] = v.x; tile[kk][rnc + 1] = v.y;
        tile[kk][rnc + 2] = v.z; tile[kk][rnc + 3] = v.w;
    }
    __syncthreads();

    const int wnn = tid >> 3, wkc = (tid & 7) * 8;
    #pragma unroll
    for (int p = 0; p < 2; ++p) {
        const int nn = p * 32 + wnn;
        bf16x8 o;
        #pragma unroll
        for (int j = 0; j < 8; ++j) o[j] = (bf16)tile[wkc + j][nn];
        *(bf16x8*)(out + (size_t)(n0 + nn) * K + k0 + wkc) = o;
    }
}

// ---------------------------------------------------------------- routing
__global__ void route_init(int* __restrict__ tok2slot, int* __restrict__ lists,
                           int* __restrict__ counts, int* __restrict__ cursors) {
    const int i = blockIdx.x * 256 + threadIdx.x;
    if (i < BB * NE)   tok2slot[i] = -1;
    if (i < ROWS_MAX)  lists[i] = 0;
    if (i < NE)        { counts[i] = 0; cursors[i] = 0; }
}

__global__ void route_count(const float* __restrict__ wcomb, int* __restrict__ counts) {
    const int t = blockIdx.x * 256 + threadIdx.x;
    const int e = blockIdx.y;
    if (wcomb[(size_t)t * NE + e] > 0.f) atomicAdd(&counts[e], 1);
}

// single block: exclusive prefix of 128-padded counts
__global__ void route_offsets(const int* __restrict__ counts, int* __restrict__ offs) {
    if (threadIdx.x == 0) {
        int o = 0;
        for (int e = 0; e < NE; ++e) { offs[e] = o; o += (counts[e] + 127) & ~127; }
        offs[NE] = o;
    }
}

__global__ void route_assign(const float* __restrict__ wcomb, const int* __restrict__ offs,
                             int* __restrict__ cursors, int* __restrict__ lists,
                             int* __restrict__ tok2slot) {
    const int t = blockIdx.x * 256 + threadIdx.x;
    const int e = blockIdx.y;
    if (wcomb[(size_t)t * NE + e] > 0.f) {
        const int pos  = atomicAdd(&cursors[e], 1);
        const int slot = offs[e] + pos;
        lists[slot] = t;
        tok2slot[(size_t)t * NE + e] = slot;
    }
}

// grid (BB), block 256: out[t] = sum_e w[t,e] * yc[slot(t,e)]  (fixed e order)
__global__ void combine_out(const int* __restrict__ tok2slot, const float* __restrict__ wcomb,
                            const float* __restrict__ yc, float* __restrict__ out) {
    const int t = blockIdx.x, tid = threadIdx.x;
    float4 acc = { 0.f, 0.f, 0.f, 0.f };
    #pragma unroll
    for (int e = 0; e < NE; ++e) {
        const int s = tok2slot[(size_t)t * NE + e];
        if (s >= 0) {
            const float w = wcomb[(size_t)t * NE + e];
            const float4 y = *(const float4*)&yc[(size_t)s * ODIM + tid * 4];
            acc.x += w * y.x; acc.y += w * y.y; acc.z += w * y.z; acc.w += w * y.w;
        }
    }
    *(float4*)&out[(size_t)t * ODIM + tid * 4] = acc;
}

// ---------------------------------------------------------------- batched compact expert GEMM
// r8-proven config: 128x128 tile, BK=32, 256 thr, 3 LDS slots (48 KB, 3 blocks/CU),
// depth-2 counted-vmcnt(4) prefetch, raw s_barrier. EPI 0 gathers A rows via lists.
// NEW (T1): bijective XCD-chunked swizzle of the (x,y) tile plane — consecutive
// dispatch ids on one XCD get contiguous tiles (A-panel L2 reuse). Per-z nwg is
// divisible by 8 for all four layers, so blockIdx.z doesn't shift the XCD phase.
// grid (N/128, BB/128, E). EPI 0: relu->Cb  1: +res->Cb  2: plain->Cb  3: ->Cf
template<int EPI>
__global__ __launch_bounds__(256, 2)
void egemm(const bf16* __restrict__ A, const bf16* __restrict__ Wt,
           const float* __restrict__ bias, const bf16* __restrict__ res,
           bf16* __restrict__ Cb, float* __restrict__ Cf,
           const int* __restrict__ offs, const int* __restrict__ lists,
           int N, int K)
{
    const int e = blockIdx.z;
    const int off  = offs[e];
    const int cntp = offs[e + 1] - off;     // 128-aligned

    // ---- XCD-chunked bijective swizzle (m204 formula) within the (x,y) plane
    const int nx = gridDim.x, nwg = nx * gridDim.y;
    const int flat = blockIdx.x + nx * blockIdx.y;
    const int qq_ = nwg / NXCD, rr_ = nwg % NXCD;
    const int xcd = flat % NXCD, lp = flat / NXCD;
    const int swz = (xcd < rr_ ? xcd * (qq_ + 1) : rr_ * (qq_ + 1) + (xcd - rr_) * qq_) + lp;
    const int bx = swz % nx, by = swz / nx;

    const int m0 = by * 128;
    if (m0 >= cntp) return;
    const int n0 = bx * 128;

    __shared__ bf16 sA[3][128 * 32];
    __shared__ bf16 sB[3][128 * 32];
    const int tid  = threadIdx.x;
    const int lane = tid & 63;
    const int wave = tid >> 6;
    const int wr = wave >> 1, wc = wave & 1;
    const int q  = lane >> 4;
    const int lr = lane & 15;

    const bf16*  Wte = Wt + (size_t)e * N * K;
    const float* be  = bias + (size_t)e * N;

    const bf16* srcA[2];
    const bf16* srcB[2];
    int dsto[2];
    #pragma unroll
    for (int i = 0; i < 2; ++i) {
        const int ch  = i * 256 + tid;
        const int row = ch >> 2, c = ch & 3;
        const int qg  = c ^ ((row >> 1) & 3);   // XOR swizzle on GLOBAL source (rule #21)
        size_t arow;
        if constexpr (EPI == 0) arow = (size_t)lists[off + m0 + row];   // gather from xb
        else                    arow = (size_t)(off + m0 + row);        // compact frame
        srcA[i] = A   + arow * K + qg * 8;
        srcB[i] = Wte + (size_t)(n0 + row) * K + qg * 8;
        dsto[i] = (i * 256 + (tid & 192)) * 8;  // wave-uniform base, lane-linear dest
    }

    f32x4 acc[4][4] = {};

    auto stage = [&](int buf, int kt) {
        const int k0 = kt << 5;
        #pragma unroll
        for (int i = 0; i < 2; ++i) {
            __builtin_amdgcn_global_load_lds(GPTR(srcA[i] + k0), LPTR(&sA[buf][dsto[i]]), 16, 0, 0);
            __builtin_amdgcn_global_load_lds(GPTR(srcB[i] + k0), LPTR(&sB[buf][dsto[i]]), 16, 0, 0);
        }
    };

    const int NT = K >> 5;          // >= 32 here
    stage(0, 0);
    stage(1, 1);

    for (int kt = 0; kt < NT; ++kt) {
        const int cur = kt % 3;
        // counted drain: tile kt's 4 loads (oldest) land; tile kt+1's 4 stay in flight
        if (kt + 1 < NT) { asm volatile("s_waitcnt vmcnt(4)" ::: "memory"); }
        else             { asm volatile("s_waitcnt vmcnt(0)" ::: "memory"); }
        __builtin_amdgcn_sched_barrier(0);
        __builtin_amdgcn_s_barrier();
        __builtin_amdgcn_sched_barrier(0);

        bf16x8 fa[4], fb[4];
        #pragma unroll
        for (int mi = 0; mi < 4; ++mi) {
            const int r = wr * 64 + mi * 16 + lr;
            const int c = q ^ ((r >> 1) & 3);
            fa[mi] = *(const bf16x8*)&sA[cur][(size_t)(r * 4 + c) * 8];
        }
        #pragma unroll
        for (int ni = 0; ni < 4; ++ni) {
            const int r = wc * 64 + ni * 16 + lr;
            const int c = q ^ ((r >> 1) & 3);
            fb[ni] = *(const bf16x8*)&sB[cur][(size_t)(r * 4 + c) * 8];
        }
        #pragma unroll
        for (int mi = 0; mi < 4; ++mi)
            #pragma unroll
            for (int ni = 0; ni < 4; ++ni)
                acc[mi][ni] = __builtin_amdgcn_mfma_f32_16x16x32_bf16(fa[mi], fb[ni], acc[mi][ni], 0, 0, 0);

        if (kt + 2 < NT) stage((kt + 2) % 3, kt + 2);
    }

    // C/D layout (m89-verified): col = lane&15, row = (lane>>4)*4 + reg
    #pragma unroll
    for (int ni = 0; ni < 4; ++ni) {
        const int c  = n0 + wc * 64 + ni * 16 + lr;
        const float bv = be[c];
        #pragma unroll
        for (int mi = 0; mi < 4; ++mi) {
            const int rloc = wr * 64 + mi * 16 + q * 4;
            #pragma unroll
            for (int j = 0; j < 4; ++j) {
                const size_t idx = (size_t)(off + m0 + rloc + j) * N + c;
                float v = acc[mi][ni][j] + bv;
                if constexpr (EPI == 0)      { Cb[idx] = (bf16)fmaxf(v, 0.f); }
                else if constexpr (EPI == 1) { Cb[idx] = (bf16)(v + (float)res[idx]); }
                else if constexpr (EPI == 2) { Cb[idx] = (bf16)v; }
                else                         { Cf[idx] = v; }
            }
        }
    }
}

// ---------------------------------------------------------------- LN + act on compact rows
template<int ACT> // 0 = relu, 1 = silu
__global__ __launch_bounds__(256)
void ln_act_bf16(const bf16* __restrict__ in, const float* __restrict__ gam,
                 const float* __restrict__ bet, bf16* __restrict__ out,
                 const int* __restrict__ offs)
{
    const int e = blockIdx.y;
    const int row = blockIdx.x;
    const int off = offs[e];
    if (row >= offs[e + 1] - off) return;
    const int tid = threadIdx.x;
    const size_t base = (size_t)(off + row) * HDIM;
    const float* g = gam + (size_t)e * HDIM;
    const float* b = bet + (size_t)e * HDIM;
    bf16x8 v = *(const bf16x8*)(in + base + tid * 8);
    float x[8], s = 0.f, ss = 0.f;
    #pragma unroll
    for (int j = 0; j < 8; ++j) { x[j] = (float)v[j]; s += x[j]; ss += x[j] * x[j]; }
    #pragma unroll
    for (int o = 1; o < 64; o <<= 1) { s += __shfl_xor(s, o); ss += __shfl_xor(ss, o); }
    __shared__ float rs[4], rss[4];
    if ((tid & 63) == 0) { rs[tid >> 6] = s; rss[tid >> 6] = ss; }
    __syncthreads();
    s  = rs[0] + rs[1] + rs[2] + rs[3];
    ss = rss[0] + rss[1] + rss[2] + rss[3];
    const float mean = s * (1.f / HDIM);
    const float var  = ss * (1.f / HDIM) - mean * mean;
    const float rstd = rsqrtf(var + 1e-5f);
    bf16x8 ov;
    #pragma unroll
    for (int j = 0; j < 8; ++j) {
        const int col = tid * 8 + j;
        float y = (x[j] - mean) * rstd * g[col] + b[col];
        if constexpr (ACT == 0) y = fmaxf(y, 0.f);
        else                    y = y / (1.f + expf(-y));
        ov[j] = (bf16)y;
    }
    *(bf16x8*)(out + base + tid * 8) = ov;
}

// ---------------------------------------------------------------- f32 gating GEMM (exact top-k)
template<int EPI> // 0=relu, 1=+res, 2=plain
__global__ __launch_bounds__(256)
void gemm_f32(const float* __restrict__ A, const float* __restrict__ Bm,
              const float* __restrict__ bias, const float* __restrict__ res,
              float* __restrict__ C, int M, int N, int K)
{
    __shared__ float As[64][17];
    __shared__ float Bs[16][64];
    const int tid = threadIdx.x;
    const int tx = tid & 15, ty = tid >> 4;
    const int n0 = blockIdx.x * 64, m0 = blockIdx.y * 64;
    float acc[4][4] = {};

    for (int k0 = 0; k0 < K; k0 += 16) {
        {
            const int r = tid >> 2, c = (tid & 3) * 4;
            const float4 va = *(const float4*)(A + (size_t)(m0 + r) * K + k0 + c);
            As[r][c] = va.x; As[r][c + 1] = va.y; As[r][c + 2] = va.z; As[r][c + 3] = va.w;
            const int rb = tid >> 4, cb = (tid & 15) * 4;
            *(float4*)&Bs[rb][cb] = *(const float4*)(Bm + (size_t)(k0 + rb) * N + n0 + cb);
        }
        __syncthreads();
        #pragma unroll
        for (int k = 0; k < 16; ++k) {
            const float4 b4 = *(const float4*)&Bs[k][tx * 4];
            float av[4];
            #pragma unroll
            for (int i = 0; i < 4; ++i) av[i] = As[ty * 4 + i][k];
            #pragma unroll
            for (int i = 0; i < 4; ++i) {
                acc[i][0] += av[i] * b4.x; acc[i][1] += av[i] * b4.y;
                acc[i][2] += av[i] * b4.z; acc[i][3] += av[i] * b4.w;
            }
        }
        __syncthreads();
    }

    const float4 b4 = *(const float4*)(bias + n0 + tx * 4);
    #pragma unroll
    for (int i = 0; i < 4; ++i) {
        const int r = m0 + ty * 4 + i;
        float o[4] = { acc[i][0] + b4.x, acc[i][1] + b4.y, acc[i][2] + b4.z, acc[i][3] + b4.w };
        if constexpr (EPI == 0) {
            #pragma unroll
            for (int j = 0; j < 4; ++j) o[j] = fmaxf(o[j], 0.f);
        } else if constexpr (EPI == 1) {
            const float4 r4 = *(const float4*)(res + (size_t)r * N + n0 + tx * 4);
            o[0] += r4.x; o[1] += r4.y; o[2] += r4.z; o[3] += r4.w;
        }
        float4 o4 = { o[0], o[1], o[2], o[3] };
        *(float4*)(C + (size_t)r * N + n0 + tx * 4) = o4;
    }
}

// split-K=2 variant for the K=1024 layer: grid (N/64, M/64, 2), raw partials
__global__ __launch_bounds__(256)
void gemm_f32_sk(const float* __restrict__ A, const float* __restrict__ Bm,
                 float* __restrict__ Cp, int M, int N, int K)
{
    __shared__ float As[64][17];
    __shared__ float Bs[16][64];
    const int tid = threadIdx.x;
    const int tx = tid & 15, ty = tid >> 4;
    const int n0 = blockIdx.x * 64, m0 = blockIdx.y * 64;
    const int kh = K >> 1;
    const int kb = blockIdx.z * kh, ke = kb + kh;
    float acc[4][4] = {};

    for (int k0 = kb; k0 < ke; k0 += 16) {
        {
            const int r = tid >> 2, c = (tid & 3) * 4;
            const float4 va = *(const float4*)(A + (size_t)(m0 + r) * K + k0 + c);
            As[r][c] = va.x; As[r][c + 1] = va.y; As[r][c + 2] = va.z; As[r][c + 3] = va.w;
            const int rb = tid >> 4, cb = (tid & 15) * 4;
            *(float4*)&Bs[rb][cb] = *(const float4*)(Bm + (size_t)(k0 + rb) * N + n0 + cb);
        }
        __syncthreads();
        #pragma unroll
        for (int k = 0; k < 16; ++k) {
            const float4 b4 = *(const float4*)&Bs[k][tx * 4];
            float av[4];
            #pragma unroll
            for (int i = 0; i < 4; ++i) av[i] = As[ty * 4 + i][k];
            #pragma unroll
            for (int i = 0; i < 4; ++i) {
                acc[i][0] += av[i] * b4.x; acc[i][1] += av[i] * b4.y;
                acc[i][2] += av[i] * b4.z; acc[i][3] += av[i] * b4.w;
            }
        }
        __syncthreads();
    }

    float* Cz = Cp + (size_t)blockIdx.z * M * N;
    #pragma unroll
    for (int i = 0; i < 4; ++i) {
        const int r = m0 + ty * 4 + i;
        float4 o4 = { acc[i][0], acc[i][1], acc[i][2], acc[i][3] };
        *(float4*)(Cz + (size_t)r * N + n0 + tx * 4) = o4;
    }
}

// out = relu(p0 + p1 + bias), [M=BB][N=GG1], grid BB*GG1/1024, block 256 (float4)
__global__ void sk_reduce_relu(const float* __restrict__ Cp, const float* __restrict__ bias,
                               float* __restrict__ C)
{
    const size_t i = ((size_t)blockIdx.x * 256 + threadIdx.x) * 4;
    const int col = (int)(i % GG1);
    const float4 a = *(const float4*)(Cp + i);
    const float4 b = *(const float4*)(Cp + (size_t)BB * GG1 + i);
    const float4 bi = *(const float4*)(bias + col);
    float4 o;
    o.x = fmaxf(a.x + b.x + bi.x, 0.f);
    o.y = fmaxf(a.y + b.y + bi.y, 0.f);
    o.z = fmaxf(a.z + b.z + bi.z, 0.f);
    o.w = fmaxf(a.w + b.w + bi.w, 0.f);
    *(float4*)(C + i) = o;
}

// ---------------------------------------------------------------- gating LN (+relu)
__global__ void ln_relu_f32_256(const float* __restrict__ in, const float* __restrict__ g,
                                const float* __restrict__ b, float* __restrict__ out)
{
    const int row = blockIdx.x, lane = threadIdx.x;
    const size_t base = (size_t)row * GG1;
    const float4 v = *(const float4*)(in + base + lane * 4);
    float s  = v.x + v.y + v.z + v.w;
    float ss = v.x * v.x + v.y * v.y + v.z * v.z + v.w * v.w;
    #pragma unroll
    for (int o = 1; o < 64; o <<= 1) { s += __shfl_xor(s, o); ss += __shfl_xor(ss, o); }
    const float mean = s * (1.f / GG1);
    const float var  = ss * (1.f / GG1) - mean * mean;
    const float rstd = rsqrtf(var + 1e-5f);
    const float4 g4 = *(const float4*)(g + lane * 4);
    const float4 b4 = *(const float4*)(b + lane * 4);
    float4 o4;
    o4.x = fmaxf((v.x - mean) * rstd * g4.x + b4.x, 0.f);
    o4.y = fmaxf((v.y - mean) * rstd * g4.y + b4.y, 0.f);
    o4.z = fmaxf((v.z - mean) * rstd * g4.z + b4.z, 0.f);
    o4.w = fmaxf((v.w - mean) * rstd * g4.w + b4.w, 0.f);
    *(float4*)(out + base + lane * 4) = o4;
}

// ---------------------------------------------------------------- gate head
__global__ void gate_head(const float* __restrict__ g2, const float* __restrict__ gwout,
                          const float* __restrict__ gbout, const float* __restrict__ temp,
                          float* __restrict__ probs_out, float* __restrict__ wout)
{
    const int row = blockIdx.x, lane = threadIdx.x;
    __shared__ float lg[NE];
    const int e = lane >> 2, part = lane & 3;
    float acc = 0.f;
    if (e < NE) {
        const float* gr = g2 + (size_t)row * GG2;
        #pragma unroll
        for (int i = 0; i < 32; ++i) {
            const int k = part * 32 + i;
            acc += gr[k] * gwout[(size_t)k * NE + e];
        }
    }
    acc += __shfl_xor(acc, 1);
    acc += __shfl_xor(acc, 2);
    if (e < NE && part == 0) lg[e] = acc + gbout[e];
    __syncthreads();
    if (lane == 0) {
        const float t = temp[0];
        float p[NE];
        float mx = -1e30f;
        #pragma unroll
        for (int i = 0; i < NE; ++i) { p[i] = lg[i] / t; mx = fmaxf(mx, p[i]); }
        float se = 0.f;
        #pragma unroll
        for (int i = 0; i < NE; ++i) { p[i] = expf(p[i] - mx); se += p[i]; }
        const float inv = 1.f / se;
        #pragma unroll
        for (int i = 0; i < NE; ++i) { p[i] *= inv; probs_out[(size_t)row * NE + i] = p[i]; }
        float qq[NE], w[NE];
        #pragma unroll
        for (int i = 0; i < NE; ++i) { qq[i] = p[i]; w[i] = 0.f; }
        float tv[4]; int ti[4]; float tsum = 0.f;
        for (int k = 0; k < 4; ++k) {        // strict > scan: lowest index wins ties (lax.top_k)
            int best = 0; float bv = qq[0];
            for (int i = 1; i < NE; ++i) if (qq[i] > bv) { bv = qq[i]; best = i; }
            tv[k] = bv; ti[k] = best; qq[best] = -1e30f; tsum += bv;
        }
        const float it = 1.f / tsum;
        for (int k = 0; k < 4; ++k) w[ti[k]] = tv[k] * it;
        #pragma unroll
        for (int i = 0; i < NE; ++i) wout[(size_t)row * NE + i] = w[i];
    }
}

// ---------------------------------------------------------------- usage + loss
__global__ void usage_mean(const float* __restrict__ probs, float* __restrict__ usage) {
    const int e = blockIdx.x, tid = threadIdx.x;
    float s = 0.f;
    for (int r = tid; r < BB; r += 256) s += probs[(size_t)r * NE + e];
    #pragma unroll
    for (int o = 1; o < 64; o <<= 1) s += __shfl_xor(s, o);
    __shared__ float ps[4];
    if ((tid & 63) == 0) ps[tid >> 6] = s;
    __syncthreads();
    if (tid == 0) usage[e] = (ps[0] + ps[1] + ps[2] + ps[3]) / (float)BB;
}

__global__ void loss_kernel(const float* __restrict__ usage, float* __restrict__ out_loss) {
    if (threadIdx.x == 0) {
        const float ideal = 1.f / 12.f;
        float kl = 0.f, var = 0.f, ent = 0.f;
        for (int e = 0; e < NE; ++e) {
            const float u = usage[e];
            kl  += ideal * (logf(ideal) - logf(u + 1e-8f));
            var += (u - ideal) * (u - ideal);
            ent -= u * logf(u + 1e-8f);
        }
        const float entl = 1.f - ent / logf(12.f);
        out_loss[0] = (0.5f * kl + 0.3f * var + 0.2f * entl) * 0.05f;
    }
}

// ---------------------------------------------------------------- launcher
extern "C" void kernel_launch(void* const* d_in, const int* in_sizes, int n_in,
                              void* d_out, int out_size, void* d_ws, size_t ws_size,
                              hipStream_t stream)
{
    const float* x      = (const float*)d_in[0];
    const float* ew_in  = (const float*)d_in[1];
    const float* eb_in  = (const float*)d_in[2];
    const float* ln1_g  = (const float*)d_in[3];
    const float* ln1_b  = (const float*)d_in[4];
    const float* ew_h1  = (const float*)d_in[5];
    const float* eb_h1  = (const float*)d_in[6];
    const float* ln2_g  = (const float*)d_in[7];
    const float* ln2_b  = (const float*)d_in[8];
    const float* ew_h2  = (const float*)d_in[9];
    const float* eb_h2  = (const float*)d_in[10];
    const float* ew_out = (const float*)d_in[11];
    const float* eb_out = (const float*)d_in[12];
    const float* gw_in  = (const float*)d_in[13];
    const float* gb_in  = (const float*)d_in[14];
    const float* gln1_g = (const float*)d_in[15];
    const float* gln1_b = (const float*)d_in[16];
    const float* gw_1   = (const float*)d_in[17];
    const float* gb_1   = (const float*)d_in[18];
    const float* gln2_g = (const float*)d_in[19];
    const float* gln2_b = (const float*)d_in[20];
    const float* gw_2   = (const float*)d_in[21];
    const float* gb_2   = (const float*)d_in[22];
    const float* gw_out = (const float*)d_in[23];
    const float* gb_out = (const float*)d_in[24];
    const float* temp   = (const float*)d_in[25];

    float* out_final = (float*)d_out;                       // [B,O]
    float* out_loss  = out_final + (size_t)BB * ODIM;       // [1]
    float* out_probs = out_loss + 1;                        // [B,E]

    char* ws = (char*)d_ws;
    size_t off = 0;
    auto alloc = [&](size_t bytes) -> void* {
        void* p = ws + off;
        off += (bytes + 255) & ~(size_t)255;
        return p;
    };

    bf16* xb     = (bf16*)alloc((size_t)BB * DDIM * 2);
    bf16* wt_in  = (bf16*)alloc((size_t)NE * HDIM * DDIM * 2);
    bf16* wt_h1  = (bf16*)alloc((size_t)NE * HDIM * HDIM * 2);
    bf16* wt_h2  = (bf16*)alloc((size_t)NE * MDIM * HDIM * 2);
    bf16* wt_out = (bf16*)alloc((size_t)NE * ODIM * MDIM * 2);
    bf16* regA   = (bf16*)alloc((size_t)ROWS_MAX * HDIM * 2);   // h0 then a2
    bf16* regB   = (bf16*)alloc((size_t)ROWS_MAX * HDIM * 2);   // a1 then h2
    bf16* h1     = (bf16*)alloc((size_t)ROWS_MAX * HDIM * 2);
    float* yc    = (float*)alloc((size_t)ROWS_MAX * ODIM * 4);
    bf16* h0 = regA; bf16* a2 = regA;
    bf16* a1 = regB; bf16* h2 = regB;
    float* skbuf = (float*)alloc((size_t)2 * BB * GG1 * 4);     // split-K partials
    float* g0    = (float*)alloc((size_t)BB * GG1 * 4);
    float* t1    = (float*)alloc((size_t)BB * GG1 * 4);
    float* g1    = (float*)alloc((size_t)BB * GG1 * 4);
    float* t2    = (float*)alloc((size_t)BB * GG1 * 4);
    float* g2b   = (float*)alloc((size_t)BB * GG2 * 4);
    float* wcomb = (float*)alloc((size_t)BB * NE * 4);
    int*   lists = (int*)alloc((size_t)ROWS_MAX * 4);
    int*   t2s   = (int*)alloc((size_t)BB * NE * 4);
    int*   counts= (int*)alloc(256);
    int*   curs  = (int*)alloc(256);
    int*   offs  = (int*)alloc(256);
    float* usage = (float*)alloc(256);

    // ---- input/weight conversion ----
    cvt_f32_bf16<<<dim3(BB * DDIM / 1024), dim3(256), 0, stream>>>(x, xb);
    transpose_cvt<<<dim3(HDIM / 64, DDIM / 64, NE), dim3(256), 0, stream>>>(ew_in,  wt_in,  DDIM, HDIM);
    transpose_cvt<<<dim3(HDIM / 64, HDIM / 64, NE), dim3(256), 0, stream>>>(ew_h1,  wt_h1,  HDIM, HDIM);
    transpose_cvt<<<dim3(MDIM / 64, HDIM / 64, NE), dim3(256), 0, stream>>>(ew_h2,  wt_h2,  HDIM, MDIM);
    transpose_cvt<<<dim3(ODIM / 64, MDIM / 64, NE), dim3(256), 0, stream>>>(ew_out, wt_out, MDIM, ODIM);

    // ---- gating (f32 for exact top-k; layer0 split-K=2) ----
    gemm_f32_sk<<<dim3(GG1 / 64, BB / 64, 2), dim3(256), 0, stream>>>(x, gw_in, skbuf, BB, GG1, DDIM);
    sk_reduce_relu<<<dim3(BB * GG1 / 1024), dim3(256), 0, stream>>>(skbuf, gb_in, g0);
    ln_relu_f32_256<<<dim3(BB), dim3(64), 0, stream>>>(g0, gln1_g, gln1_b, t1);
    gemm_f32<1><<<dim3(GG1 / 64, BB / 64), dim3(256), 0, stream>>>(t1, gw_1,  gb_1,  g0,      g1,  BB, GG1, GG1);
    ln_relu_f32_256<<<dim3(BB), dim3(64), 0, stream>>>(g1, gln2_g, gln2_b, t2);
    gemm_f32<2><<<dim3(GG2 / 64, BB / 64), dim3(256), 0, stream>>>(t2, gw_2,  gb_2,  nullptr, g2b, BB, GG2, GG1);
    gate_head<<<dim3(BB), dim3(64), 0, stream>>>(g2b, gw_out, gb_out, temp, out_probs, wcomb);
    usage_mean<<<dim3(NE), dim3(256), 0, stream>>>(out_probs, usage);
    loss_kernel<<<dim3(1), dim3(64), 0, stream>>>(usage, out_loss);

    // ---- routing (count -> prefix offsets -> assign) ----
    route_init<<<dim3((BB * NE + 255) / 256), dim3(256), 0, stream>>>(t2s, lists, counts, curs);
    route_count<<<dim3(BB / 256, NE), dim3(256), 0, stream>>>(wcomb, counts);
    route_offsets<<<dim3(1), dim3(64), 0, stream>>>(counts, offs);
    route_assign<<<dim3(BB / 256, NE), dim3(256), 0, stream>>>(wcomb, offs, curs, lists, t2s);

    // ---- compact experts (depth-2 prefetch + XCD swizzle; layer0 fuses gather) ----
    egemm<0><<<dim3(HDIM / 128, BB / 128, NE), dim3(256), 0, stream>>>(
        xb, wt_in, eb_in, nullptr, h0, nullptr, offs, lists, HDIM, DDIM);
    ln_act_bf16<0><<<dim3(BB, NE), dim3(256), 0, stream>>>(h0, ln1_g, ln1_b, a1, offs);
    egemm<1><<<dim3(HDIM / 128, BB / 128, NE), dim3(256), 0, stream>>>(
        a1, wt_h1, eb_h1, h0, h1, nullptr, offs, lists, HDIM, HDIM);
    ln_act_bf16<1><<<dim3(BB, NE), dim3(256), 0, stream>>>(h1, ln2_g, ln2_b, a2, offs);
    egemm<2><<<dim3(MDIM / 128, BB / 128, NE), dim3(256), 0, stream>>>(
        a2, wt_h2, eb_h2, nullptr, h2, nullptr, offs, lists, MDIM, HDIM);
    egemm<3><<<dim3(ODIM / 128, BB / 128, NE), dim3(256), 0, stream>>>(
        h2, wt_out, eb_out, nullptr, nullptr, yc, offs, lists, ODIM, MDIM);

    // ---- combine ----
    combine_out<<<dim3(BB), dim3(256), 0, stream>>>(t2s, wcomb, yc, out_final);
}

// Round 11
// 851.936 us; speedup vs baseline: 1.6487x; 1.6487x over previous
//
#include <hip/hip_runtime.h>
#include <cstdint>
#include <cstddef>

typedef __bf16 bf16;
typedef __bf16 bf16x4 __attribute__((ext_vector_type(4)));
typedef __bf16 bf16x8 __attribute__((ext_vector_type(8)));
typedef float  f32x4  __attribute__((ext_vector_type(4)));

#define NE   12     // experts
#define DDIM 1024   // D
#define HDIM 2048   // H
#define MDIM 1024   // H/2
#define ODIM 1024   // O
#define GG1  256
#define GG2  128
#define BB   4096
// Sum of per-expert counts == 4*BB == 16384 exactly. Padded to 128/expert:
// total rows <= 16384 + 12*127 = 17908 < 18432.
#define ROWS_MAX 18432

#define GPTR(p) ((const __attribute__((address_space(1))) void*)(p))
#define LPTR(p) ((__attribute__((address_space(3))) void*)(p))

// ---------------------------------------------------------------- converts
__global__ void cvt_f32_bf16(const float* __restrict__ in, bf16* __restrict__ out) {
    size_t i = ((size_t)blockIdx.x * 256 + threadIdx.x) * 4;
    float4 v = *(const float4*)(in + i);
    bf16x4 o = { (bf16)v.x, (bf16)v.y, (bf16)v.z, (bf16)v.w };
    *(bf16x4*)(out + i) = o;
}

// in: [E][K,N] f32 -> out: [E][N,K] bf16. 64x64 tiles, 256 threads. (r8-proven)
__global__ __launch_bounds__(256)
void transpose_cvt(const float* __restrict__ in, bf16* __restrict__ out,
                   int K, int N) {
    __shared__ float tile[64][65];
    const size_t eo = (size_t)blockIdx.z * K * N;
    in  += eo;
    out += eo;
    const int n0 = blockIdx.x * 64, k0 = blockIdx.y * 64;
    const int tid = threadIdx.x;

    const int rkk = tid >> 4, rnc = (tid & 15) * 4;
    #pragma unroll
    for (int p = 0; p < 4; ++p) {
        const int kk = p * 16 + rkk;
        const float4 v = *(const float4*)(in + (size_t)(k0 + kk) * N + n0 + rnc);
        tile[kk][rnc] = v.x; tile[kk][rnc + 1] = v.y;
        tile[kk][rnc + 2] = v.z; tile[kk][rnc + 3] = v.w;
    }
    __syncthreads();

    const int wnn = tid >> 3, wkc = (tid & 7) * 8;
    #pragma unroll
    for (int p = 0; p < 2; ++p) {
        const int nn = p * 32 + wnn;
        bf16x8 o;
        #pragma unroll
        for (int j = 0; j < 8; ++j) o[j] = (bf16)tile[wkc + j][nn];
        *(bf16x8*)(out + (size_t)(n0 + nn) * K + k0 + wkc) = o;
    }
}

// ---------------------------------------------------------------- routing
__global__ void route_init(int* __restrict__ tok2slot, int* __restrict__ lists,
                           int* __restrict__ counts, int* __restrict__ cursors) {
    const int i = blockIdx.x * 256 + threadIdx.x;
    if (i < BB * NE)   tok2slot[i] = -1;
    if (i < ROWS_MAX)  lists[i] = 0;
    if (i < NE)        { counts[i] = 0; cursors[i] = 0; }
}

__global__ void route_count(const float* __restrict__ wcomb, int* __restrict__ counts) {
    const int t = blockIdx.x * 256 + threadIdx.x;
    const int e = blockIdx.y;
    if (wcomb[(size_t)t * NE + e] > 0.f) atomicAdd(&counts[e], 1);
}

// single block: exclusive prefix of 128-padded counts
__global__ void route_offsets(const int* __restrict__ counts, int* __restrict__ offs) {
    if (threadIdx.x == 0) {
        int o = 0;
        for (int e = 0; e < NE; ++e) { offs[e] = o; o += (counts[e] + 127) & ~127; }
        offs[NE] = o;
    }
}

__global__ void route_assign(const float* __restrict__ wcomb, const int* __restrict__ offs,
                             int* __restrict__ cursors, int* __restrict__ lists,
                             int* __restrict__ tok2slot) {
    const int t = blockIdx.x * 256 + threadIdx.x;
    const int e = blockIdx.y;
    if (wcomb[(size_t)t * NE + e] > 0.f) {
        const int pos  = atomicAdd(&cursors[e], 1);
        const int slot = offs[e] + pos;
        lists[slot] = t;
        tok2slot[(size_t)t * NE + e] = slot;
    }
}

// grid (BB), block 256: out[t] = sum_e w[t,e] * yc[slot(t,e)]  (fixed e order)
__global__ void combine_out(const int* __restrict__ tok2slot, const float* __restrict__ wcomb,
                            const float* __restrict__ yc, float* __restrict__ out) {
    const int t = blockIdx.x, tid = threadIdx.x;
    float4 acc = { 0.f, 0.f, 0.f, 0.f };
    #pragma unroll
    for (int e = 0; e < NE; ++e) {
        const int s = tok2slot[(size_t)t * NE + e];
        if (s >= 0) {
            const float w = wcomb[(size_t)t * NE + e];
            const float4 y = *(const float4*)&yc[(size_t)s * ODIM + tid * 4];
            acc.x += w * y.x; acc.y += w * y.y; acc.z += w * y.z; acc.w += w * y.w;
        }
    }
    *(float4*)&out[(size_t)t * ODIM + tid * 4] = acc;
}

// ---------------------------------------------------------------- batched compact expert GEMM
// r8-proven config (no block swizzle — r10 showed XCD-chunked swizzle concentrates
// the live prefix of the padded grid onto 3/8 XCDs): 128x128 tile, BK=32, 256 thr,
// 3 LDS slots (48 KB, 3 blocks/CU), depth-2 counted-vmcnt(4), raw s_barrier.
// EPI 0 gathers A rows via lists (per-lane global source for global_load_lds).
// grid (N/128, BB/128, E). EPI 0: relu->Cb  1: +res->Cb  2: plain->Cb  3: ->Cf
template<int EPI>
__global__ __launch_bounds__(256, 2)
void egemm(const bf16* __restrict__ A, const bf16* __restrict__ Wt,
           const float* __restrict__ bias, const bf16* __restrict__ res,
           bf16* __restrict__ Cb, float* __restrict__ Cf,
           const int* __restrict__ offs, const int* __restrict__ lists,
           int N, int K)
{
    const int e = blockIdx.z;
    const int off  = offs[e];
    const int cntp = offs[e + 1] - off;     // 128-aligned
    const int m0 = blockIdx.y * 128;
    if (m0 >= cntp) return;
    const int n0 = blockIdx.x * 128;

    __shared__ bf16 sA[3][128 * 32];
    __shared__ bf16 sB[3][128 * 32];
    const int tid  = threadIdx.x;
    const int lane = tid & 63;
    const int wave = tid >> 6;
    const int wr = wave >> 1, wc = wave & 1;
    const int q  = lane >> 4;
    const int lr = lane & 15;

    const bf16*  Wte = Wt + (size_t)e * N * K;
    const float* be  = bias + (size_t)e * N;

    const bf16* srcA[2];
    const bf16* srcB[2];
    int dsto[2];
    #pragma unroll
    for (int i = 0; i < 2; ++i) {
        const int ch  = i * 256 + tid;
        const int row = ch >> 2, c = ch & 3;
        const int qg  = c ^ ((row >> 1) & 3);   // XOR swizzle on GLOBAL source (rule #21)
        size_t arow;
        if constexpr (EPI == 0) arow = (size_t)lists[off + m0 + row];   // gather from xb
        else                    arow = (size_t)(off + m0 + row);        // compact frame
        srcA[i] = A   + arow * K + qg * 8;
        srcB[i] = Wte + (size_t)(n0 + row) * K + qg * 8;
        dsto[i] = (i * 256 + (tid & 192)) * 8;  // wave-uniform base, lane-linear dest
    }

    f32x4 acc[4][4] = {};

    auto stage = [&](int buf, int kt) {
        const int k0 = kt << 5;
        #pragma unroll
        for (int i = 0; i < 2; ++i) {
            __builtin_amdgcn_global_load_lds(GPTR(srcA[i] + k0), LPTR(&sA[buf][dsto[i]]), 16, 0, 0);
            __builtin_amdgcn_global_load_lds(GPTR(srcB[i] + k0), LPTR(&sB[buf][dsto[i]]), 16, 0, 0);
        }
    };

    const int NT = K >> 5;          // >= 32 here
    stage(0, 0);
    stage(1, 1);

    for (int kt = 0; kt < NT; ++kt) {
        const int cur = kt % 3;
        // counted drain: tile kt's 4 loads (oldest) land; tile kt+1's 4 stay in flight
        if (kt + 1 < NT) { asm volatile("s_waitcnt vmcnt(4)" ::: "memory"); }
        else             { asm volatile("s_waitcnt vmcnt(0)" ::: "memory"); }
        __builtin_amdgcn_sched_barrier(0);
        __builtin_amdgcn_s_barrier();
        __builtin_amdgcn_sched_barrier(0);

        bf16x8 fa[4], fb[4];
        #pragma unroll
        for (int mi = 0; mi < 4; ++mi) {
            const int r = wr * 64 + mi * 16 + lr;
            const int c = q ^ ((r >> 1) & 3);
            fa[mi] = *(const bf16x8*)&sA[cur][(size_t)(r * 4 + c) * 8];
        }
        #pragma unroll
        for (int ni = 0; ni < 4; ++ni) {
            const int r = wc * 64 + ni * 16 + lr;
            const int c = q ^ ((r >> 1) & 3);
            fb[ni] = *(const bf16x8*)&sB[cur][(size_t)(r * 4 + c) * 8];
        }
        #pragma unroll
        for (int mi = 0; mi < 4; ++mi)
            #pragma unroll
            for (int ni = 0; ni < 4; ++ni)
                acc[mi][ni] = __builtin_amdgcn_mfma_f32_16x16x32_bf16(fa[mi], fb[ni], acc[mi][ni], 0, 0, 0);

        if (kt + 2 < NT) stage((kt + 2) % 3, kt + 2);
    }

    // C/D layout (m89-verified): col = lane&15, row = (lane>>4)*4 + reg
    #pragma unroll
    for (int ni = 0; ni < 4; ++ni) {
        const int c  = n0 + wc * 64 + ni * 16 + lr;
        const float bv = be[c];
        #pragma unroll
        for (int mi = 0; mi < 4; ++mi) {
            const int rloc = wr * 64 + mi * 16 + q * 4;
            #pragma unroll
            for (int j = 0; j < 4; ++j) {
                const size_t idx = (size_t)(off + m0 + rloc + j) * N + c;
                float v = acc[mi][ni][j] + bv;
                if constexpr (EPI == 0)      { Cb[idx] = (bf16)fmaxf(v, 0.f); }
                else if constexpr (EPI == 1) { Cb[idx] = (bf16)(v + (float)res[idx]); }
                else if constexpr (EPI == 2) { Cb[idx] = (bf16)v; }
                else                         { Cf[idx] = v; }
            }
        }
    }
}

// ---------------------------------------------------------------- LN + act on compact rows
template<int ACT> // 0 = relu, 1 = silu
__global__ __launch_bounds__(256)
void ln_act_bf16(const bf16* __restrict__ in, const float* __restrict__ gam,
                 const float* __restrict__ bet, bf16* __restrict__ out,
                 const int* __restrict__ offs)
{
    const int e = blockIdx.y;
    const int row = blockIdx.x;
    const int off = offs[e];
    if (row >= offs[e + 1] - off) return;
    const int tid = threadIdx.x;
    const size_t base = (size_t)(off + row) * HDIM;
    const float* g = gam + (size_t)e * HDIM;
    const float* b = bet + (size_t)e * HDIM;
    bf16x8 v = *(const bf16x8*)(in + base + tid * 8);
    float x[8], s = 0.f, ss = 0.f;
    #pragma unroll
    for (int j = 0; j < 8; ++j) { x[j] = (float)v[j]; s += x[j]; ss += x[j] * x[j]; }
    #pragma unroll
    for (int o = 1; o < 64; o <<= 1) { s += __shfl_xor(s, o); ss += __shfl_xor(ss, o); }
    __shared__ float rs[4], rss[4];
    if ((tid & 63) == 0) { rs[tid >> 6] = s; rss[tid >> 6] = ss; }
    __syncthreads();
    s  = rs[0] + rs[1] + rs[2] + rs[3];
    ss = rss[0] + rss[1] + rss[2] + rss[3];
    const float mean = s * (1.f / HDIM);
    const float var  = ss * (1.f / HDIM) - mean * mean;
    const float rstd = rsqrtf(var + 1e-5f);
    bf16x8 ov;
    #pragma unroll
    for (int j = 0; j < 8; ++j) {
        const int col = tid * 8 + j;
        float y = (x[j] - mean) * rstd * g[col] + b[col];
        if constexpr (ACT == 0) y = fmaxf(y, 0.f);
        else                    y = y / (1.f + expf(-y));
        ov[j] = (bf16)y;
    }
    *(bf16x8*)(out + base + tid * 8) = ov;
}

// ---------------------------------------------------------------- f32 gating GEMM (exact top-k)
template<int EPI> // 0=relu, 1=+res, 2=plain
__global__ __launch_bounds__(256)
void gemm_f32(const float* __restrict__ A, const float* __restrict__ Bm,
              const float* __restrict__ bias, const float* __restrict__ res,
              float* __restrict__ C, int M, int N, int K)
{
    __shared__ float As[64][17];
    __shared__ float Bs[16][64];
    const int tid = threadIdx.x;
    const int tx = tid & 15, ty = tid >> 4;
    const int n0 = blockIdx.x * 64, m0 = blockIdx.y * 64;
    float acc[4][4] = {};

    for (int k0 = 0; k0 < K; k0 += 16) {
        {
            const int r = tid >> 2, c = (tid & 3) * 4;
            const float4 va = *(const float4*)(A + (size_t)(m0 + r) * K + k0 + c);
            As[r][c] = va.x; As[r][c + 1] = va.y; As[r][c + 2] = va.z; As[r][c + 3] = va.w;
            const int rb = tid >> 4, cb = (tid & 15) * 4;
            *(float4*)&Bs[rb][cb] = *(const float4*)(Bm + (size_t)(k0 + rb) * N + n0 + cb);
        }
        __syncthreads();
        #pragma unroll
        for (int k = 0; k < 16; ++k) {
            const float4 b4 = *(const float4*)&Bs[k][tx * 4];
            float av[4];
            #pragma unroll
            for (int i = 0; i < 4; ++i) av[i] = As[ty * 4 + i][k];
            #pragma unroll
            for (int i = 0; i < 4; ++i) {
                acc[i][0] += av[i] * b4.x; acc[i][1] += av[i] * b4.y;
                acc[i][2] += av[i] * b4.z; acc[i][3] += av[i] * b4.w;
            }
        }
        __syncthreads();
    }

    const float4 b4 = *(const float4*)(bias + n0 + tx * 4);
    #pragma unroll
    for (int i = 0; i < 4; ++i) {
        const int r = m0 + ty * 4 + i;
        float o[4] = { acc[i][0] + b4.x, acc[i][1] + b4.y, acc[i][2] + b4.z, acc[i][3] + b4.w };
        if constexpr (EPI == 0) {
            #pragma unroll
            for (int j = 0; j < 4; ++j) o[j] = fmaxf(o[j], 0.f);
        } else if constexpr (EPI == 1) {
            const float4 r4 = *(const float4*)(res + (size_t)r * N + n0 + tx * 4);
            o[0] += r4.x; o[1] += r4.y; o[2] += r4.z; o[3] += r4.w;
        }
        float4 o4 = { o[0], o[1], o[2], o[3] };
        *(float4*)(C + (size_t)r * N + n0 + tx * 4) = o4;
    }
}

// split-K=2 variant for the K=1024 layer: grid (N/64, M/64, 2), raw partials
__global__ __launch_bounds__(256)
void gemm_f32_sk(const float* __restrict__ A, const float* __restrict__ Bm,
                 float* __restrict__ Cp, int M, int N, int K)
{
    __shared__ float As[64][17];
    __shared__ float Bs[16][64];
    const int tid = threadIdx.x;
    const int tx = tid & 15, ty = tid >> 4;
    const int n0 = blockIdx.x * 64, m0 = blockIdx.y * 64;
    const int kh = K >> 1;
    const int kb = blockIdx.z * kh, ke = kb + kh;
    float acc[4][4] = {};

    for (int k0 = kb; k0 < ke; k0 += 16) {
        {
            const int r = tid >> 2, c = (tid & 3) * 4;
            const float4 va = *(const float4*)(A + (size_t)(m0 + r) * K + k0 + c);
            As[r][c] = va.x; As[r][c + 1] = va.y; As[r][c + 2] = va.z; As[r][c + 3] = va.w;
            const int rb = tid >> 4, cb = (tid & 15) * 4;
            *(float4*)&Bs[rb][cb] = *(const float4*)(Bm + (size_t)(k0 + rb) * N + n0 + cb);
        }
        __syncthreads();
        #pragma unroll
        for (int k = 0; k < 16; ++k) {
            const float4 b4 = *(const float4*)&Bs[k][tx * 4];
            float av[4];
            #pragma unroll
            for (int i = 0; i < 4; ++i) av[i] = As[ty * 4 + i][k];
            #pragma unroll
            for (int i = 0; i < 4; ++i) {
                acc[i][0] += av[i] * b4.x; acc[i][1] += av[i] * b4.y;
                acc[i][2] += av[i] * b4.z; acc[i][3] += av[i] * b4.w;
            }
        }
        __syncthreads();
    }

    float* Cz = Cp + (size_t)blockIdx.z * M * N;
    #pragma unroll
    for (int i = 0; i < 4; ++i) {
        const int r = m0 + ty * 4 + i;
        float4 o4 = { acc[i][0], acc[i][1], acc[i][2], acc[i][3] };
        *(float4*)(Cz + (size_t)r * N + n0 + tx * 4) = o4;
    }
}

// out = relu(p0 + p1 + bias), [M=BB][N=GG1], grid BB*GG1/1024, block 256 (float4)
__global__ void sk_reduce_relu(const float* __restrict__ Cp, const float* __restrict__ bias,
                               float* __restrict__ C)
{
    const size_t i = ((size_t)blockIdx.x * 256 + threadIdx.x) * 4;
    const int col = (int)(i % GG1);
    const float4 a = *(const float4*)(Cp + i);
    const float4 b = *(const float4*)(Cp + (size_t)BB * GG1 + i);
    const float4 bi = *(const float4*)(bias + col);
    float4 o;
    o.x = fmaxf(a.x + b.x + bi.x, 0.f);
    o.y = fmaxf(a.y + b.y + bi.y, 0.f);
    o.z = fmaxf(a.z + b.z + bi.z, 0.f);
    o.w = fmaxf(a.w + b.w + bi.w, 0.f);
    *(float4*)(C + i) = o;
}

// ---------------------------------------------------------------- gating LN (+relu)
__global__ void ln_relu_f32_256(const float* __restrict__ in, const float* __restrict__ g,
                                const float* __restrict__ b, float* __restrict__ out)
{
    const int row = blockIdx.x, lane = threadIdx.x;
    const size_t base = (size_t)row * GG1;
    const float4 v = *(const float4*)(in + base + lane * 4);
    float s  = v.x + v.y + v.z + v.w;
    float ss = v.x * v.x + v.y * v.y + v.z * v.z + v.w * v.w;
    #pragma unroll
    for (int o = 1; o < 64; o <<= 1) { s += __shfl_xor(s, o); ss += __shfl_xor(ss, o); }
    const float mean = s * (1.f / GG1);
    const float var  = ss * (1.f / GG1) - mean * mean;
    const float rstd = rsqrtf(var + 1e-5f);
    const float4 g4 = *(const float4*)(g + lane * 4);
    const float4 b4 = *(const float4*)(b + lane * 4);
    float4 o4;
    o4.x = fmaxf((v.x - mean) * rstd * g4.x + b4.x, 0.f);
    o4.y = fmaxf((v.y - mean) * rstd * g4.y + b4.y, 0.f);
    o4.z = fmaxf((v.z - mean) * rstd * g4.z + b4.z, 0.f);
    o4.w = fmaxf((v.w - mean) * rstd * g4.w + b4.w, 0.f);
    *(float4*)(out + base + lane * 4) = o4;
}

// ---------------------------------------------------------------- gate head
__global__ void gate_head(const float* __restrict__ g2, const float* __restrict__ gwout,
                          const float* __restrict__ gbout, const float* __restrict__ temp,
                          float* __restrict__ probs_out, float* __restrict__ wout)
{
    const int row = blockIdx.x, lane = threadIdx.x;
    __shared__ float lg[NE];
    const int e = lane >> 2, part = lane & 3;
    float acc = 0.f;
    if (e < NE) {
        const float* gr = g2 + (size_t)row * GG2;
        #pragma unroll
        for (int i = 0; i < 32; ++i) {
            const int k = part * 32 + i;
            acc += gr[k] * gwout[(size_t)k * NE + e];
        }
    }
    acc += __shfl_xor(acc, 1);
    acc += __shfl_xor(acc, 2);
    if (e < NE && part == 0) lg[e] = acc + gbout[e];
    __syncthreads();
    if (lane == 0) {
        const float t = temp[0];
        float p[NE];
        float mx = -1e30f;
        #pragma unroll
        for (int i = 0; i < NE; ++i) { p[i] = lg[i] / t; mx = fmaxf(mx, p[i]); }
        float se = 0.f;
        #pragma unroll
        for (int i = 0; i < NE; ++i) { p[i] = expf(p[i] - mx); se += p[i]; }
        const float inv = 1.f / se;
        #pragma unroll
        for (int i = 0; i < NE; ++i) { p[i] *= inv; probs_out[(size_t)row * NE + i] = p[i]; }
        float qq[NE], w[NE];
        #pragma unroll
        for (int i = 0; i < NE; ++i) { qq[i] = p[i]; w[i] = 0.f; }
        float tv[4]; int ti[4]; float tsum = 0.f;
        for (int k = 0; k < 4; ++k) {        // strict > scan: lowest index wins ties (lax.top_k)
            int best = 0; float bv = qq[0];
            for (int i = 1; i < NE; ++i) if (qq[i] > bv) { bv = qq[i]; best = i; }
            tv[k] = bv; ti[k] = best; qq[best] = -1e30f; tsum += bv;
        }
        const float it = 1.f / tsum;
        for (int k = 0; k < 4; ++k) w[ti[k]] = tv[k] * it;
        #pragma unroll
        for (int i = 0; i < NE; ++i) wout[(size_t)row * NE + i] = w[i];
    }
}

// ---------------------------------------------------------------- usage + loss
__global__ void usage_mean(const float* __restrict__ probs, float* __restrict__ usage) {
    const int e = blockIdx.x, tid = threadIdx.x;
    float s = 0.f;
    for (int r = tid; r < BB; r += 256) s += probs[(size_t)r * NE + e];
    #pragma unroll
    for (int o = 1; o < 64; o <<= 1) s += __shfl_xor(s, o);
    __shared__ float ps[4];
    if ((tid & 63) == 0) ps[tid >> 6] = s;
    __syncthreads();
    if (tid == 0) usage[e] = (ps[0] + ps[1] + ps[2] + ps[3]) / (float)BB;
}

__global__ void loss_kernel(const float* __restrict__ usage, float* __restrict__ out_loss) {
    if (threadIdx.x == 0) {
        const float ideal = 1.f / 12.f;
        float kl = 0.f, var = 0.f, ent = 0.f;
        for (int e = 0; e < NE; ++e) {
            const float u = usage[e];
            kl  += ideal * (logf(ideal) - logf(u + 1e-8f));
            var += (u - ideal) * (u - ideal);
            ent -= u * logf(u + 1e-8f);
        }
        const float entl = 1.f - ent / logf(12.f);
        out_loss[0] = (0.5f * kl + 0.3f * var + 0.2f * entl) * 0.05f;
    }
}

// ---------------------------------------------------------------- launcher
extern "C" void kernel_launch(void* const* d_in, const int* in_sizes, int n_in,
                              void* d_out, int out_size, void* d_ws, size_t ws_size,
                              hipStream_t stream)
{
    const float* x      = (const float*)d_in[0];
    const float* ew_in  = (const float*)d_in[1];
    const float* eb_in  = (const float*)d_in[2];
    const float* ln1_g  = (const float*)d_in[3];
    const float* ln1_b  = (const float*)d_in[4];
    const float* ew_h1  = (const float*)d_in[5];
    const float* eb_h1  = (const float*)d_in[6];
    const float* ln2_g  = (const float*)d_in[7];
    const float* ln2_b  = (const float*)d_in[8];
    const float* ew_h2  = (const float*)d_in[9];
    const float* eb_h2  = (const float*)d_in[10];
    const float* ew_out = (const float*)d_in[11];
    const float* eb_out = (const float*)d_in[12];
    const float* gw_in  = (const float*)d_in[13];
    const float* gb_in  = (const float*)d_in[14];
    const float* gln1_g = (const float*)d_in[15];
    const float* gln1_b = (const float*)d_in[16];
    const float* gw_1   = (const float*)d_in[17];
    const float* gb_1   = (const float*)d_in[18];
    const float* gln2_g = (const float*)d_in[19];
    const float* gln2_b = (const float*)d_in[20];
    const float* gw_2   = (const float*)d_in[21];
    const float* gb_2   = (const float*)d_in[22];
    const float* gw_out = (const float*)d_in[23];
    const float* gb_out = (const float*)d_in[24];
    const float* temp   = (const float*)d_in[25];

    float* out_final = (float*)d_out;                       // [B,O]
    float* out_loss  = out_final + (size_t)BB * ODIM;       // [1]
    float* out_probs = out_loss + 1;                        // [B,E]

    char* ws = (char*)d_ws;
    size_t off = 0;
    auto alloc = [&](size_t bytes) -> void* {
        void* p = ws + off;
        off += (bytes + 255) & ~(size_t)255;
        return p;
    };

    bf16* xb     = (bf16*)alloc((size_t)BB * DDIM * 2);
    bf16* wt_in  = (bf16*)alloc((size_t)NE * HDIM * DDIM * 2);
    bf16* wt_h1  = (bf16*)alloc((size_t)NE * HDIM * HDIM * 2);
    bf16* wt_h2  = (bf16*)alloc((size_t)NE * MDIM * HDIM * 2);
    bf16* wt_out = (bf16*)alloc((size_t)NE * ODIM * MDIM * 2);
    bf16* regA   = (bf16*)alloc((size_t)ROWS_MAX * HDIM * 2);   // h0 then a2
    bf16* regB   = (bf16*)alloc((size_t)ROWS_MAX * HDIM * 2);   // a1 then h2
    bf16* h1     = (bf16*)alloc((size_t)ROWS_MAX * HDIM * 2);
    float* yc    = (float*)alloc((size_t)ROWS_MAX * ODIM * 4);
    bf16* h0 = regA; bf16* a2 = regA;
    bf16* a1 = regB; bf16* h2 = regB;
    float* skbuf = (float*)alloc((size_t)2 * BB * GG1 * 4);     // split-K partials
    float* g0    = (float*)alloc((size_t)BB * GG1 * 4);
    float* t1    = (float*)alloc((size_t)BB * GG1 * 4);
    float* g1    = (float*)alloc((size_t)BB * GG1 * 4);
    float* t2    = (float*)alloc((size_t)BB * GG1 * 4);
    float* g2b   = (float*)alloc((size_t)BB * GG2 * 4);
    float* wcomb = (float*)alloc((size_t)BB * NE * 4);
    int*   lists = (int*)alloc((size_t)ROWS_MAX * 4);
    int*   t2s   = (int*)alloc((size_t)BB * NE * 4);
    int*   counts= (int*)alloc(256);
    int*   curs  = (int*)alloc(256);
    int*   offs  = (int*)alloc(256);
    float* usage = (float*)alloc(256);

    // ---- input/weight conversion ----
    cvt_f32_bf16<<<dim3(BB * DDIM / 1024), dim3(256), 0, stream>>>(x, xb);
    transpose_cvt<<<dim3(HDIM / 64, DDIM / 64, NE), dim3(256), 0, stream>>>(ew_in,  wt_in,  DDIM, HDIM);
    transpose_cvt<<<dim3(HDIM / 64, HDIM / 64, NE), dim3(256), 0, stream>>>(ew_h1,  wt_h1,  HDIM, HDIM);
    transpose_cvt<<<dim3(MDIM / 64, HDIM / 64, NE), dim3(256), 0, stream>>>(ew_h2,  wt_h2,  HDIM, MDIM);
    transpose_cvt<<<dim3(ODIM / 64, MDIM / 64, NE), dim3(256), 0, stream>>>(ew_out, wt_out, MDIM, ODIM);

    // ---- gating (f32 for exact top-k; layer0 split-K=2) ----
    gemm_f32_sk<<<dim3(GG1 / 64, BB / 64, 2), dim3(256), 0, stream>>>(x, gw_in, skbuf, BB, GG1, DDIM);
    sk_reduce_relu<<<dim3(BB * GG1 / 1024), dim3(256), 0, stream>>>(skbuf, gb_in, g0);
    ln_relu_f32_256<<<dim3(BB), dim3(64), 0, stream>>>(g0, gln1_g, gln1_b, t1);
    gemm_f32<1><<<dim3(GG1 / 64, BB / 64), dim3(256), 0, stream>>>(t1, gw_1,  gb_1,  g0,      g1,  BB, GG1, GG1);
    ln_relu_f32_256<<<dim3(BB), dim3(64), 0, stream>>>(g1, gln2_g, gln2_b, t2);
    gemm_f32<2><<<dim3(GG2 / 64, BB / 64), dim3(256), 0, stream>>>(t2, gw_2,  gb_2,  nullptr, g2b, BB, GG2, GG1);
    gate_head<<<dim3(BB), dim3(64), 0, stream>>>(g2b, gw_out, gb_out, temp, out_probs, wcomb);
    usage_mean<<<dim3(NE), dim3(256), 0, stream>>>(out_probs, usage);
    loss_kernel<<<dim3(1), dim3(64), 0, stream>>>(usage, out_loss);

    // ---- routing (count -> prefix offsets -> assign) ----
    route_init<<<dim3((BB * NE + 255) / 256), dim3(256), 0, stream>>>(t2s, lists, counts, curs);
    route_count<<<dim3(BB / 256, NE), dim3(256), 0, stream>>>(wcomb, counts);
    route_offsets<<<dim3(1), dim3(64), 0, stream>>>(counts, offs);
    route_assign<<<dim3(BB / 256, NE), dim3(256), 0, stream>>>(wcomb, offs, curs, lists, t2s);

    // ---- compact experts (r8 depth-2 prefetch, natural block order; layer0 fuses gather) ----
    egemm<0><<<dim3(HDIM / 128, BB / 128, NE), dim3(256), 0, stream>>>(
        xb, wt_in, eb_in, nullptr, h0, nullptr, offs, lists, HDIM, DDIM);
    ln_act_bf16<0><<<dim3(BB, NE), dim3(256), 0, stream>>>(h0, ln1_g, ln1_b, a1, offs);
    egemm<1><<<dim3(HDIM / 128, BB / 128, NE), dim3(256), 0, stream>>>(
        a1, wt_h1, eb_h1, h0, h1, nullptr, offs, lists, HDIM, HDIM);
    ln_act_bf16<1><<<dim3(BB, NE), dim3(256), 0, stream>>>(h1, ln2_g, ln2_b, a2, offs);
    egemm<2><<<dim3(MDIM / 128, BB / 128, NE), dim3(256), 0, stream>>>(
        a2, wt_h2, eb_h2, nullptr, h2, nullptr, offs, lists, MDIM, HDIM);
    egemm<3><<<dim3(ODIM / 128, BB / 128, NE), dim3(256), 0, stream>>>(
        h2, wt_out, eb_out, nullptr, nullptr, yc, offs, lists, ODIM, MDIM);

    // ---- combine ----
    combine_out<<<dim3(BB), dim3(256), 0, stream>>>(t2s, wcomb, yc, out_final);
}